// Round 15
// baseline (212.592 us; speedup 1.0000x reference)
//
#include <hip/hip_runtime.h>
#include <hip/hip_bf16.h>
#include <math.h>

// Problem constants
#define PS    32768
#define DIN   1024
#define DMID  512
#define DATT  128
#define KMASK 16384
#define LKEEP 16384

typedef unsigned short u16;
typedef __attribute__((ext_vector_type(8))) short short8;
typedef __attribute__((ext_vector_type(4))) float f32x4;

__device__ __forceinline__ u16 f2bf(float f){
  unsigned x = __float_as_uint(f);
  unsigned r = (x + 0x7fffu + ((x >> 16) & 1u)) >> 16;  // RNE
  return (u16)r;
}
__device__ __forceinline__ u16 f2bf_hw(float f){
  __hip_bfloat16 h = __float2bfloat16(f);    // RNE; pairs fuse to v_cvt_pk_bf16_f32
  return *reinterpret_cast<u16*>(&h);
}
__device__ __forceinline__ float bf2f(u16 u){
  return __uint_as_float(((unsigned)u) << 16);
}
// monotonic key: larger float -> larger unsigned
__device__ __forceinline__ unsigned fkey(float f){
  unsigned b = __float_as_uint(f);
  return (b & 0x80000000u) ? ~b : (b | 0x80000000u);
}

#define GLDS16(g,l) __builtin_amdgcn_global_load_lds( \
    (const __attribute__((address_space(1))) void*)(g), \
    (__attribute__((address_space(3))) void*)(l), 16, 0, 0)

// ---------------------------------------------------------------------------
// MEASUREMENT ROUND: every kernel except k_sel_hist and k_gemm1g runs its body
// TWICE (idempotent pass loop — identical values recomputed/rewritten).
// dur - 155.8 = tail_sum  ->  gaps = 155.8 - 65(gemm1g) - tail_sum - 2(hist).
// ctrl ints: [2]=C (cutoff key), [3]=eqidx_thr.
// ---------------------------------------------------------------------------

// Prep: weight transposes (f32->bf16) + zero hist/ctrl. 576 blocks. x2.
__global__ __launch_bounds__(256) void k_prep(const float* __restrict__ Wemb,
                                              u16* __restrict__ wet,
                                              const float* __restrict__ Wa1,
                                              u16* __restrict__ wa1t,
                                              int* __restrict__ zbuf){
  __shared__ float tile[32][33];
  const int b = blockIdx.x, t = threadIdx.x;
  const int flat = b * 256 + t;
  if (flat < 16384 + 64) zbuf[flat] = 0;
  const int tx = t & 31, ty = t >> 5;
  for (int pass = 0; pass < 2; pass++){
    __syncthreads();
    if (b < 512){
      const int c0 = (b & 15) * 32, r0 = (b >> 4) * 32;   // Wemb [1024][512]
      for (int i = 0; i < 32; i += 8)
        tile[ty + i][tx] = Wemb[(size_t)(r0 + ty + i) * DMID + c0 + tx];
      __syncthreads();
      for (int i = 0; i < 32; i += 8)
        wet[(size_t)(c0 + ty + i) * DIN + r0 + tx] = f2bf(tile[tx][ty + i]);
    } else {
      const int b2 = b - 512;                              // Wa1 [512][128]
      const int c0 = (b2 & 3) * 32, r0 = (b2 >> 2) * 32;
      for (int i = 0; i < 32; i += 8)
        tile[ty + i][tx] = Wa1[(size_t)(r0 + ty + i) * DATT + c0 + tx];
      __syncthreads();
      for (int i = 0; i < 32; i += 8)
        wa1t[(size_t)(c0 + ty + i) * DMID + r0 + tx] = f2bf(tile[tx][ty + i]);
    }
  }
}

// Stage 1: 14-bit global histogram. 128 blocks x 256. (NOT doubled: atomics.)
__global__ __launch_bounds__(256) void k_sel_hist(const float* __restrict__ attn,
                                                  int* __restrict__ hist){
  const int i = blockIdx.x * 256 + threadIdx.x;
  const unsigned u = fkey(attn[i]);
  atomicAdd(&hist[u >> 18], 1);
}

// Stage 2+3: scan + refine. One block x 1024. x2 (idempotent: ctrl same).
__global__ __launch_bounds__(1024) void k_sel_scanrefine(const float* __restrict__ attn,
                                                         const int* __restrict__ hist,
                                                         int* __restrict__ ctrl){
  __shared__ int suf[1024];
  __shared__ unsigned ck[4096];
  __shared__ int ci[4096];
  __shared__ int sh_B, sh_kp, cnt;
  const int t = threadIdx.x;
  for (int pass = 0; pass < 2; pass++){
    __syncthreads();
    int local[16]; int s = 0;
    const int base = t * 16;
    for (int j = 0; j < 16; j++){ local[j] = hist[base + j]; s += local[j]; }
    suf[t] = s; __syncthreads();
    for (int off = 1; off < 1024; off <<= 1){
      int v = (t + off < 1024) ? suf[t + off] : 0;
      __syncthreads();
      suf[t] += v;
      __syncthreads();
    }
    const int above = (t < 1023) ? suf[t + 1] : 0;
    if (above < KMASK && KMASK <= suf[t]){
      int cum = above;
      for (int b = 15; b >= 0; b--){
        int c = local[b];
        if (cum + c >= KMASK){ sh_B = base + b; sh_kp = KMASK - cum; break; }
        cum += c;
      }
    }
    if (t == 0) cnt = 0;
    __syncthreads();
    const unsigned B = (unsigned)sh_B;
    const int kp = sh_kp;
    for (int i = t; i < PS; i += 1024){
      unsigned u = fkey(attn[i]);
      if ((u >> 18) == B){
        int p = atomicAdd(&cnt, 1);
        if (p < 4096){ ck[p] = u; ci[p] = i; }
      }
    }
    __syncthreads();
    int n = cnt; if (n > 4096) n = 4096;
    for (int p = t; p < n; p += 1024){
      const unsigned mk = ck[p]; const int mi = ci[p];
      int rank = 0;
      for (int j = 0; j < n; j++){
        const unsigned kj = ck[j];
        rank += (kj > mk) || (kj == mk && ci[j] < mi);
      }
      if (rank == kp - 1){ ctrl[2] = (int)mk; ctrl[3] = mi; }
    }
  }
}

// Stage 4: merged cnt+write. 32 blocks x 1024. x2 (idempotent).
__global__ __launch_bounds__(1024) void k_sel_cntwrite(const float* __restrict__ attn,
                                                       const int* __restrict__ ctrl,
                                                       int* __restrict__ keep_ids){
  __shared__ int red[1024];
  __shared__ int wbase[16];
  __shared__ int sh_base;
  const int t = threadIdx.x, b = blockIdx.x;
  for (int pass = 0; pass < 2; pass++){
    __syncthreads();
    const unsigned C = (unsigned)ctrl[2];
    const int thr = ctrl[3];
    const int i = b * 1024 + t;
    const unsigned u = fkey(attn[i]);
    const bool kept = (u < C) || (u == C && i > thr);
    const unsigned long long bal = __ballot(kept);
    const int lane = t & 63, w = t >> 6;
    if (lane == 0) wbase[w] = __popcll(bal);
    int cnt = 0;
    for (int j = 0; j < b; j++){
      const int i2 = j * 1024 + t;
      const unsigned u2 = fkey(attn[i2]);
      cnt += (u2 < C) || (u2 == C && i2 > thr);
    }
    red[t] = cnt; __syncthreads();
    for (int st = 512; st > 0; st >>= 1){ if (t < st) red[t] += red[t + st]; __syncthreads(); }
    if (t == 0){
      sh_base = red[0];
      int run = 0;
      for (int j = 0; j < 16; j++){ int c = wbase[j]; wbase[j] = run; run += c; }
    }
    __syncthreads();
    if (kept){
      const int lr = __popcll(bal & ((1ull << lane) - 1ull));
      keep_ids[sh_base + wbase[w] + lr] = i;
    }
  }
}

// ---------------------------------------------------------------------------
// GEMM1 fused gather (exact R6-proven body, single pass).
// ---------------------------------------------------------------------------
__global__ __launch_bounds__(256) void k_gemm1g(const float* __restrict__ xg,
                                                const int* __restrict__ keep,
                                                const u16* __restrict__ wet,
                                                const float* __restrict__ bemb,
                                                u16* __restrict__ hbf){
  __shared__ __align__(16) u16 As[128 * 32];
  __shared__ __align__(16) u16 Bs[128 * 32];
  const int t = threadIdx.x;
  const int wid = t >> 6, lane = t & 63;
  const int g = lane >> 4, li = lane & 15;
  const int m_ = blockIdx.x;
  const int by = (m_ & 7) + 8 * (m_ >> 5);
  const int bx = (m_ >> 3) & 3;
  const int brow = by * 128, bcol = bx * 128;
  const int wrow0 = (wid >> 1) * 64, wcol0 = (wid & 1) * 64;

  f32x4 acc[4][4];
  for (int mm = 0; mm < 4; mm++)
    for (int nn = 0; nn < 4; nn++)
      acc[mm][nn] = (f32x4){0.f, 0.f, 0.f, 0.f};

  const int rsub = t >> 3, csub = t & 7;
  const float* gA[4];
#pragma unroll
  for (int q = 0; q < 4; q++){
    const int rid = keep[brow + q * 32 + rsub];
    gA[q] = xg + (size_t)rid * DIN + csub * 4;
  }
  const int r4 = lane >> 2, cB = lane & 3;
  const u16* gB = wet + ((size_t)(bcol + wid * 32 + r4) * DIN + cB * 8);
  u16* lB = Bs + wid * 1024;

  for (int k0 = 0; k0 < DIN; k0 += 32){
    float4 av[4];
#pragma unroll
    for (int q = 0; q < 4; q++) av[q] = *(const float4*)(gA[q] + k0);
    GLDS16(gB + k0,            lB);
    GLDS16(gB + 16 * DIN + k0, lB + 512);
#pragma unroll
    for (int q = 0; q < 4; q++){
      ushort4 pk;
      pk.x = f2bf_hw(av[q].x); pk.y = f2bf_hw(av[q].y);
      pk.z = f2bf_hw(av[q].z); pk.w = f2bf_hw(av[q].w);
      *(ushort4*)&As[(q * 32 + rsub) * 32 + csub * 4] = pk;
    }
    __syncthreads();
    short8 a[4], b[4];
#pragma unroll
    for (int mm = 0; mm < 4; mm++)
      a[mm] = *(const short8*)&As[(wrow0 + mm * 16 + li) * 32 + g * 8];
#pragma unroll
    for (int nn = 0; nn < 4; nn++)
      b[nn] = *(const short8*)&Bs[(wcol0 + nn * 16 + li) * 32 + g * 8];
    for (int mm = 0; mm < 4; mm++)
      for (int nn = 0; nn < 4; nn++)
        acc[mm][nn] = __builtin_amdgcn_mfma_f32_16x16x32_bf16(a[mm], b[nn], acc[mm][nn], 0, 0, 0);
    __syncthreads();
  }

  for (int nn = 0; nn < 4; nn++){
    const int col = bcol + wcol0 + nn * 16 + li;
    const float be = bemb[col];
    for (int mm = 0; mm < 4; mm++){
      const int row0 = brow + wrow0 + mm * 16 + g * 4;
      f32x4 v = acc[mm][nn];
      for (int r = 0; r < 4; r++){
        float val = v[r] + be;
        if (val < 0.f) val = 0.f;
        hbf[(size_t)(row0 + r) * DMID + col] = f2bf(val);
      }
    }
  }
}

// ---------------------------------------------------------------------------
// GEMM2 + fused exact-gelu + W_a2 dot. x2 (idempotent).
// ---------------------------------------------------------------------------
__global__ __launch_bounds__(256) void k_gemm2(const u16* __restrict__ hbf,
                                               const u16* __restrict__ wa1t,
                                               const float* __restrict__ ba1,
                                               const float* __restrict__ wa2,
                                               const float* __restrict__ ba2,
                                               float* __restrict__ s_out){
  __shared__ __align__(16) u16 As[64 * 32];
  __shared__ __align__(16) u16 Bs[128 * 32];
  const int t = threadIdx.x;
  const int wid = t >> 6, lane = t & 63;
  const int g = lane >> 4, li = lane & 15;
  const int brow = blockIdx.x * 64;
  const int wrow0 = (wid >> 1) * 32, wcol0 = (wid & 1) * 64;

  const int r4 = lane >> 2, c4 = lane & 3;
  const u16* gA = hbf  + ((size_t)(brow + wid * 16 + r4) * DMID + c4 * 8);
  const u16* gB = wa1t + ((size_t)(wid * 32 + r4) * DMID + c4 * 8);
  u16* lA = As + wid * 512;
  u16* lB = Bs + wid * 1024;

  for (int pass = 0; pass < 2; pass++){
    __syncthreads();
    f32x4 acc[2][4];
    for (int m = 0; m < 2; m++)
      for (int n = 0; n < 4; n++)
        acc[m][n] = (f32x4){0.f, 0.f, 0.f, 0.f};

    for (int k0 = 0; k0 < DMID; k0 += 32){
      GLDS16(gA + k0,             lA);
      GLDS16(gB + k0,             lB);
      GLDS16(gB + 16 * DMID + k0, lB + 512);
      __syncthreads();
      short8 a[2], b[4];
      for (int m = 0; m < 2; m++)
        a[m] = *(const short8*)&As[(wrow0 + m * 16 + li) * 32 + g * 8];
      for (int n = 0; n < 4; n++)
        b[n] = *(const short8*)&Bs[(wcol0 + n * 16 + li) * 32 + g * 8];
      for (int m = 0; m < 2; m++)
        for (int n = 0; n < 4; n++)
          acc[m][n] = __builtin_amdgcn_mfma_f32_16x16x32_bf16(a[m], b[n], acc[m][n], 0, 0, 0);
      __syncthreads();
    }

    float rsum[2][4] = {{0.f,0.f,0.f,0.f},{0.f,0.f,0.f,0.f}};
    for (int n = 0; n < 4; n++){
      const int col = wcol0 + n * 16 + li;
      const float b1 = ba1[col], w2 = wa2[col];
      for (int m = 0; m < 2; m++){
        f32x4 v = acc[m][n];
        for (int r = 0; r < 4; r++){
          float xv = v[r] + b1;
          float ge = 0.5f * xv * (1.0f + erff(xv * 0.70710678118654752f)); // exact gelu
          rsum[m][r] += ge * w2;
        }
      }
    }
    const float bb = ba2[0];
    for (int m = 0; m < 2; m++){
      for (int r = 0; r < 4; r++){
        float v = rsum[m][r];
        v += __shfl_xor(v, 1); v += __shfl_xor(v, 2);
        v += __shfl_xor(v, 4); v += __shfl_xor(v, 8);
        if (li == 0) s_out[brow + wrow0 + m * 16 + g * 4 + r] = v + bb;
      }
    }
  }
}

// ---------------------------------------------------------------------------
// Softmax weights over 16384 scores. One block. x2 (idempotent).
// ---------------------------------------------------------------------------
__global__ __launch_bounds__(1024) void k_softmax(const float* __restrict__ s,
                                                  float* __restrict__ w){
  __shared__ float red[1024];
  const int t = threadIdx.x;
  for (int pass = 0; pass < 2; pass++){
    __syncthreads();
    float m = -INFINITY;
    for (int i = t; i < LKEEP; i += 1024) m = fmaxf(m, s[i]);
    red[t] = m; __syncthreads();
    for (int st = 512; st > 0; st >>= 1){ if (t < st) red[t] = fmaxf(red[t], red[t + st]); __syncthreads(); }
    m = red[0]; __syncthreads();
    float z = 0.f;
    for (int i = t; i < LKEEP; i += 1024) z += expf(s[i] - m);
    red[t] = z; __syncthreads();
    for (int st = 512; st > 0; st >>= 1){ if (t < st) red[t] += red[t + st]; __syncthreads(); }
    const float invZ = 1.0f / red[0];
    for (int i = t; i < LKEEP; i += 1024) w[i] = expf(s[i] - m) * invZ;
  }
}

// ---------------------------------------------------------------------------
// feat partials: grid (8 colblk x 64 rowblk). x2 (idempotent).
// ---------------------------------------------------------------------------
__global__ __launch_bounds__(256) void k_feat1(const u16* __restrict__ hbf,
                                               const float* __restrict__ w,
                                               float* __restrict__ partial){
  __shared__ float red[256 * 8];
  const int t = threadIdx.x;
  const int colg = t & 7, rowpar = t >> 3;
  const int c0 = blockIdx.x * 64;
  const int j0 = blockIdx.y * 256;
  for (int pass = 0; pass < 2; pass++){
    __syncthreads();
    float acc[8] = {0.f,0.f,0.f,0.f,0.f,0.f,0.f,0.f};
    for (int j = j0 + rowpar; j < j0 + 256; j += 32){
      const float wj = w[j];
      short8 hv = *(const short8*)&hbf[(size_t)j * DMID + c0 + colg * 8];
      for (int c = 0; c < 8; c++) acc[c] += wj * bf2f((u16)hv[c]);
    }
    for (int c = 0; c < 8; c++) red[t * 8 + c] = acc[c];
    __syncthreads();
    for (int st = 128; st >= 8; st >>= 1){
      if (t < st){ for (int c = 0; c < 8; c++) red[t * 8 + c] += red[(t + st) * 8 + c]; }
      __syncthreads();
    }
    if (t < 8){
      for (int c = 0; c < 8; c++)
        partial[(size_t)blockIdx.y * DMID + c0 + t * 8 + c] = red[t * 8 + c];
    }
  }
}

// ---------------------------------------------------------------------------
// Final: feat reduce + logits + soft-CE loss. One block x 512. x2 (idempotent).
// ---------------------------------------------------------------------------
__global__ __launch_bounds__(512) void k_final(const float* __restrict__ partial,
                                               const float* __restrict__ teach,
                                               const float* __restrict__ Wp,
                                               const float* __restrict__ bp,
                                               float* __restrict__ out){
  __shared__ float red[512];
  const int t = threadIdx.x;
  for (int pass = 0; pass < 2; pass++){
    __syncthreads();
    float f = 0.f;
    for (int rb = 0; rb < 64; rb++) f += partial[(size_t)rb * DMID + t];
    const float td = teach[t];

    red[t] = f; __syncthreads();
    for (int st = 256; st > 0; st >>= 1){ if (t < st) red[t] = fmaxf(red[t], red[t + st]); __syncthreads(); }
    const float mf = red[0]; __syncthreads();

    red[t] = td; __syncthreads();
    for (int st = 256; st > 0; st >>= 1){ if (t < st) red[t] = fmaxf(red[t], red[t + st]); __syncthreads(); }
    const float mt = red[0]; __syncthreads();

    red[t] = expf(f - mf); __syncthreads();
    for (int st = 256; st > 0; st >>= 1){ if (t < st) red[t] += red[t + st]; __syncthreads(); }
    const float Zf = red[0]; __syncthreads();

    const float pt = expf(td - mt);
    red[t] = pt; __syncthreads();
    for (int st = 256; st > 0; st >>= 1){ if (t < st) red[t] += red[t + st]; __syncthreads(); }
    const float Zt = red[0]; __syncthreads();

    red[t] = pt * f; __syncthreads();
    for (int st = 256; st > 0; st >>= 1){ if (t < st) red[t] += red[t + st]; __syncthreads(); }
    const float S1 = red[0]; __syncthreads();

    red[t] = f * Wp[t * 2 + 0]; __syncthreads();
    for (int st = 256; st > 0; st >>= 1){ if (t < st) red[t] += red[t + st]; __syncthreads(); }
    const float L0 = red[0]; __syncthreads();

    red[t] = f * Wp[t * 2 + 1]; __syncthreads();
    for (int st = 256; st > 0; st >>= 1){ if (t < st) red[t] += red[t + st]; __syncthreads(); }
    const float L1 = red[0];

    if (t == 0){
      out[0] = L0 + bp[0];
      out[1] = L1 + bp[1];
      out[2] = (mf + logf(Zf)) - S1 / Zt;
    }
    __syncthreads();
  }
}

// ---------------------------------------------------------------------------
// ws layout (bytes):
//   [0)        keep_ids int[16384] | [65536) s f32[16384] | [131072) wgt f32[16384]
//   [200704)   wet bf16[512][1024] | [1249280) wa1t bf16[128][512]
//   [1380352)  scr: hist int[16384] + ctrl int[64] (selection phase);
//              partial f32[64][512] @+0 (feat phase) — disjoint in time
//   [34934784) hbf bf16[16384][512]
// ---------------------------------------------------------------------------
extern "C" void kernel_launch(void* const* d_in, const int* in_sizes, int n_in,
                              void* d_out, int out_size, void* d_ws, size_t ws_size,
                              hipStream_t stream){
  const float* x     = (const float*)d_in[0];
  const float* attn  = (const float*)d_in[1];
  const float* teach = (const float*)d_in[2];
  const float* Wemb  = (const float*)d_in[3];
  const float* bemb  = (const float*)d_in[4];
  const float* Wa1   = (const float*)d_in[5];
  const float* ba1   = (const float*)d_in[6];
  const float* Wa2   = (const float*)d_in[7];
  const float* ba2   = (const float*)d_in[8];
  const float* Wp    = (const float*)d_in[9];
  const float* bp    = (const float*)d_in[10];
  float* out = (float*)d_out;

  char* ws = (char*)d_ws;
  int*   keep = (int*)(ws + 0);
  float* s    = (float*)(ws + 65536);
  float* wgt  = (float*)(ws + 131072);
  u16*   wet  = (u16*)(ws + 200704);
  u16*   wa1t = (u16*)(ws + 200704 + 1048576);
  char*  scr  = ws + 200704 + 1048576 + 131072;
  u16*   hbf  = (u16*)(ws + 200704 + 1048576 + 131072 + 33554432);

  int*   hist    = (int*)scr;
  int*   ctrl    = hist + 16384;
  float* partial = (float*)scr;   // reused after selection+gemm1

  k_prep<<<dim3(576), dim3(256), 0, stream>>>(Wemb, wet, Wa1, wa1t, hist);
  k_sel_hist<<<dim3(128), dim3(256), 0, stream>>>(attn, hist);
  k_sel_scanrefine<<<dim3(1), dim3(1024), 0, stream>>>(attn, hist, ctrl);
  k_sel_cntwrite<<<dim3(32), dim3(1024), 0, stream>>>(attn, ctrl, keep);
  k_gemm1g<<<dim3(512), dim3(256), 0, stream>>>(x, keep, wet, bemb, hbf);
  k_gemm2<<<dim3(LKEEP / 64), dim3(256), 0, stream>>>(hbf, wa1t, ba1, Wa2, ba2, s);
  k_softmax<<<dim3(1), dim3(1024), 0, stream>>>(s, wgt);
  k_feat1<<<dim3(8, 64), dim3(256), 0, stream>>>(hbf, wgt, partial);
  k_final<<<dim3(1), dim3(512), 0, stream>>>(partial, teach, Wp, bp, out);
}

// Round 16
// 153.048 us; speedup vs baseline: 1.3891x; 1.3891x over previous
//
#include <hip/hip_runtime.h>
#include <hip/hip_bf16.h>
#include <math.h>

// Problem constants
#define PS    32768
#define DIN   1024
#define DMID  512
#define DATT  128
#define KMASK 16384
#define LKEEP 16384

typedef unsigned short u16;
typedef __attribute__((ext_vector_type(8))) short short8;
typedef __attribute__((ext_vector_type(4))) float f32x4;

__device__ __forceinline__ u16 f2bf(float f){
  unsigned x = __float_as_uint(f);
  unsigned r = (x + 0x7fffu + ((x >> 16) & 1u)) >> 16;  // RNE
  return (u16)r;
}
__device__ __forceinline__ u16 f2bf_hw(float f){
  __hip_bfloat16 h = __float2bfloat16(f);    // RNE; pairs fuse to v_cvt_pk_bf16_f32
  return *reinterpret_cast<u16*>(&h);
}
__device__ __forceinline__ float bf2f(u16 u){
  return __uint_as_float(((unsigned)u) << 16);
}
// monotonic key: larger float -> larger unsigned
__device__ __forceinline__ unsigned fkey(float f){
  unsigned b = __float_as_uint(f);
  return (b & 0x80000000u) ? ~b : (b | 0x80000000u);
}

#define GLDS16(g,l) __builtin_amdgcn_global_load_lds( \
    (const __attribute__((address_space(1))) void*)(g), \
    (__attribute__((address_space(3))) void*)(l), 16, 0, 0)

// ---------------------------------------------------------------------------
// Prep: weight transposes (f32->bf16) + zero hist. 576 blocks.
// ---------------------------------------------------------------------------
__global__ __launch_bounds__(256) void k_prep(const float* __restrict__ Wemb,
                                              u16* __restrict__ wet,
                                              const float* __restrict__ Wa1,
                                              u16* __restrict__ wa1t,
                                              int* __restrict__ zbuf){
  __shared__ float tile[32][33];
  const int b = blockIdx.x, t = threadIdx.x;
  const int flat = b * 256 + t;
  if (flat < 16384) zbuf[flat] = 0;
  const int tx = t & 31, ty = t >> 5;
  if (b < 512){
    const int c0 = (b & 15) * 32, r0 = (b >> 4) * 32;   // Wemb [1024][512]
    for (int i = 0; i < 32; i += 8)
      tile[ty + i][tx] = Wemb[(size_t)(r0 + ty + i) * DMID + c0 + tx];
    __syncthreads();
    for (int i = 0; i < 32; i += 8)
      wet[(size_t)(c0 + ty + i) * DIN + r0 + tx] = f2bf(tile[tx][ty + i]);
  } else {
    const int b2 = b - 512;                              // Wa1 [512][128]
    const int c0 = (b2 & 3) * 32, r0 = (b2 >> 2) * 32;
    for (int i = 0; i < 32; i += 8)
      tile[ty + i][tx] = Wa1[(size_t)(r0 + ty + i) * DATT + c0 + tx];
    __syncthreads();
    for (int i = 0; i < 32; i += 8)
      wa1t[(size_t)(c0 + ty + i) * DMID + r0 + tx] = f2bf(tile[tx][ty + i]);
  }
}

// Stage 1: 14-bit global histogram. 128 blocks x 256.
__global__ __launch_bounds__(256) void k_sel_hist(const float* __restrict__ attn,
                                                  int* __restrict__ hist){
  const int i = blockIdx.x * 256 + threadIdx.x;
  const unsigned u = fkey(attn[i]);
  atomicAdd(&hist[u >> 18], 1);
}

// ---------------------------------------------------------------------------
// Stage 2 (fused scan+refine+cnt+write): 32 blocks x 1024.
// Every block REDUNDANTLY computes (deterministic, identical):
//   (a) suffix-scan of 16384 bins -> cutoff bin B + in-bin rank kp;
//   (b) collect bin-B candidates from L2-hot attn -> rank-select (key desc,
//       idx asc) -> exact cutoff C and tie-threshold index thr.
// Then each block performs stable compaction of its own 1024-elem chunk
// (prior-chunk counts recomputed, L2-hot). No ctrl round-trip, no spin.
// ---------------------------------------------------------------------------
__global__ __launch_bounds__(1024) void k_sel_resolve(const float* __restrict__ attn,
                                                      const int* __restrict__ hist,
                                                      int* __restrict__ keep_ids){
  __shared__ int suf[1024];
  __shared__ unsigned ck[4096];
  __shared__ int ci[4096];
  __shared__ int sh_B, sh_kp, cnt;
  __shared__ unsigned sh_C;
  __shared__ int sh_thr;
  __shared__ int wbase[16];
  __shared__ int sh_base;
  const int t = threadIdx.x, b = blockIdx.x;

  // (a) suffix-scan of hist
  int local[16]; int s = 0;
  const int base = t * 16;
  for (int j = 0; j < 16; j++){ local[j] = hist[base + j]; s += local[j]; }
  suf[t] = s; __syncthreads();
  for (int off = 1; off < 1024; off <<= 1){
    int v = (t + off < 1024) ? suf[t + off] : 0;
    __syncthreads();
    suf[t] += v;
    __syncthreads();
  }
  const int above = (t < 1023) ? suf[t + 1] : 0;
  if (above < KMASK && KMASK <= suf[t]){
    int cum = above;
    for (int bb = 15; bb >= 0; bb--){
      int c = local[bb];
      if (cum + c >= KMASK){ sh_B = base + bb; sh_kp = KMASK - cum; break; }
      cum += c;
    }
  }
  if (t == 0) cnt = 0;
  __syncthreads();
  const unsigned B = (unsigned)sh_B;
  const int kp = sh_kp;

  // (b) collect candidates + rank-select (order-independent result)
  for (int i = t; i < PS; i += 1024){
    unsigned u = fkey(attn[i]);
    if ((u >> 18) == B){
      int p = atomicAdd(&cnt, 1);
      if (p < 4096){ ck[p] = u; ci[p] = i; }
    }
  }
  __syncthreads();
  int n = cnt; if (n > 4096) n = 4096;
  for (int p = t; p < n; p += 1024){
    const unsigned mk = ck[p]; const int mi = ci[p];
    int rank = 0;
    for (int j = 0; j < n; j++){
      const unsigned kj = ck[j];
      rank += (kj > mk) || (kj == mk && ci[j] < mi);
    }
    if (rank == kp - 1){ sh_C = mk; sh_thr = mi; }
  }
  __syncthreads();
  const unsigned C = sh_C;
  const int thr = sh_thr;

  // (c) stable compaction of this block's chunk
  const int i = b * 1024 + t;
  const unsigned u = fkey(attn[i]);
  const bool kept = (u < C) || (u == C && i > thr);
  const unsigned long long bal = __ballot(kept);
  const int lane = t & 63, w = t >> 6;
  if (lane == 0) wbase[w] = __popcll(bal);
  int cnt2 = 0;
  for (int j = t; j < b * 1024; j += 1024){
    const unsigned u2 = fkey(attn[j]);
    cnt2 += (u2 < C) || (u2 == C && j > thr);
  }
  suf[t] = cnt2; __syncthreads();
  for (int st = 512; st > 0; st >>= 1){ if (t < st) suf[t] += suf[t + st]; __syncthreads(); }
  if (t == 0){
    sh_base = suf[0];
    int run = 0;
    for (int j = 0; j < 16; j++){ int c = wbase[j]; wbase[j] = run; run += c; }
  }
  __syncthreads();
  if (kept){
    const int lr = __popcll(bal & ((1ull << lane) - 1ull));
    keep_ids[sh_base + wbase[w] + lr] = i;
  }
}

// ---------------------------------------------------------------------------
// GEMM1 fused gather (exact R6-proven body).
// ---------------------------------------------------------------------------
__global__ __launch_bounds__(256) void k_gemm1g(const float* __restrict__ xg,
                                                const int* __restrict__ keep,
                                                const u16* __restrict__ wet,
                                                const float* __restrict__ bemb,
                                                u16* __restrict__ hbf){
  __shared__ __align__(16) u16 As[128 * 32];
  __shared__ __align__(16) u16 Bs[128 * 32];
  const int t = threadIdx.x;
  const int wid = t >> 6, lane = t & 63;
  const int g = lane >> 4, li = lane & 15;
  const int m_ = blockIdx.x;
  const int by = (m_ & 7) + 8 * (m_ >> 5);
  const int bx = (m_ >> 3) & 3;
  const int brow = by * 128, bcol = bx * 128;
  const int wrow0 = (wid >> 1) * 64, wcol0 = (wid & 1) * 64;

  f32x4 acc[4][4];
  for (int mm = 0; mm < 4; mm++)
    for (int nn = 0; nn < 4; nn++)
      acc[mm][nn] = (f32x4){0.f, 0.f, 0.f, 0.f};

  const int rsub = t >> 3, csub = t & 7;
  const float* gA[4];
#pragma unroll
  for (int q = 0; q < 4; q++){
    const int rid = keep[brow + q * 32 + rsub];
    gA[q] = xg + (size_t)rid * DIN + csub * 4;
  }
  const int r4 = lane >> 2, cB = lane & 3;
  const u16* gB = wet + ((size_t)(bcol + wid * 32 + r4) * DIN + cB * 8);
  u16* lB = Bs + wid * 1024;

  for (int k0 = 0; k0 < DIN; k0 += 32){
    float4 av[4];
#pragma unroll
    for (int q = 0; q < 4; q++) av[q] = *(const float4*)(gA[q] + k0);
    GLDS16(gB + k0,            lB);
    GLDS16(gB + 16 * DIN + k0, lB + 512);
#pragma unroll
    for (int q = 0; q < 4; q++){
      ushort4 pk;
      pk.x = f2bf_hw(av[q].x); pk.y = f2bf_hw(av[q].y);
      pk.z = f2bf_hw(av[q].z); pk.w = f2bf_hw(av[q].w);
      *(ushort4*)&As[(q * 32 + rsub) * 32 + csub * 4] = pk;
    }
    __syncthreads();
    short8 a[4], b[4];
#pragma unroll
    for (int mm = 0; mm < 4; mm++)
      a[mm] = *(const short8*)&As[(wrow0 + mm * 16 + li) * 32 + g * 8];
#pragma unroll
    for (int nn = 0; nn < 4; nn++)
      b[nn] = *(const short8*)&Bs[(wcol0 + nn * 16 + li) * 32 + g * 8];
    for (int mm = 0; mm < 4; mm++)
      for (int nn = 0; nn < 4; nn++)
        acc[mm][nn] = __builtin_amdgcn_mfma_f32_16x16x32_bf16(a[mm], b[nn], acc[mm][nn], 0, 0, 0);
    __syncthreads();
  }

  for (int nn = 0; nn < 4; nn++){
    const int col = bcol + wcol0 + nn * 16 + li;
    const float be = bemb[col];
    for (int mm = 0; mm < 4; mm++){
      const int row0 = brow + wrow0 + mm * 16 + g * 4;
      f32x4 v = acc[mm][nn];
      for (int r = 0; r < 4; r++){
        float val = v[r] + be;
        if (val < 0.f) val = 0.f;
        hbf[(size_t)(row0 + r) * DMID + col] = f2bf(val);
      }
    }
  }
}

// ---------------------------------------------------------------------------
// GEMM2 + fused exact-gelu + W_a2 dot.
// ---------------------------------------------------------------------------
__global__ __launch_bounds__(256) void k_gemm2(const u16* __restrict__ hbf,
                                               const u16* __restrict__ wa1t,
                                               const float* __restrict__ ba1,
                                               const float* __restrict__ wa2,
                                               const float* __restrict__ ba2,
                                               float* __restrict__ s_out){
  __shared__ __align__(16) u16 As[64 * 32];
  __shared__ __align__(16) u16 Bs[128 * 32];
  const int t = threadIdx.x;
  const int wid = t >> 6, lane = t & 63;
  const int g = lane >> 4, li = lane & 15;
  const int brow = blockIdx.x * 64;
  const int wrow0 = (wid >> 1) * 32, wcol0 = (wid & 1) * 64;

  f32x4 acc[2][4];
  for (int m = 0; m < 2; m++)
    for (int n = 0; n < 4; n++)
      acc[m][n] = (f32x4){0.f, 0.f, 0.f, 0.f};

  const int r4 = lane >> 2, c4 = lane & 3;
  const u16* gA = hbf  + ((size_t)(brow + wid * 16 + r4) * DMID + c4 * 8);
  const u16* gB = wa1t + ((size_t)(wid * 32 + r4) * DMID + c4 * 8);
  u16* lA = As + wid * 512;
  u16* lB = Bs + wid * 1024;

  for (int k0 = 0; k0 < DMID; k0 += 32){
    GLDS16(gA + k0,             lA);
    GLDS16(gB + k0,             lB);
    GLDS16(gB + 16 * DMID + k0, lB + 512);
    __syncthreads();
    short8 a[2], b[4];
    for (int m = 0; m < 2; m++)
      a[m] = *(const short8*)&As[(wrow0 + m * 16 + li) * 32 + g * 8];
    for (int n = 0; n < 4; n++)
      b[n] = *(const short8*)&Bs[(wcol0 + n * 16 + li) * 32 + g * 8];
    for (int m = 0; m < 2; m++)
      for (int n = 0; n < 4; n++)
        acc[m][n] = __builtin_amdgcn_mfma_f32_16x16x32_bf16(a[m], b[n], acc[m][n], 0, 0, 0);
    __syncthreads();
  }

  float rsum[2][4] = {{0.f,0.f,0.f,0.f},{0.f,0.f,0.f,0.f}};
  for (int n = 0; n < 4; n++){
    const int col = wcol0 + n * 16 + li;
    const float b1 = ba1[col], w2 = wa2[col];
    for (int m = 0; m < 2; m++){
      f32x4 v = acc[m][n];
      for (int r = 0; r < 4; r++){
        float xv = v[r] + b1;
        float ge = 0.5f * xv * (1.0f + erff(xv * 0.70710678118654752f)); // exact gelu
        rsum[m][r] += ge * w2;
      }
    }
  }
  const float bb = ba2[0];
  for (int m = 0; m < 2; m++){
    for (int r = 0; r < 4; r++){
      float v = rsum[m][r];
      v += __shfl_xor(v, 1); v += __shfl_xor(v, 2);
      v += __shfl_xor(v, 4); v += __shfl_xor(v, 8);
      if (li == 0) s_out[brow + wrow0 + m * 16 + g * 4 + r] = v + bb;
    }
  }
}

// ---------------------------------------------------------------------------
// Softmax weights over 16384 scores. One block.
// ---------------------------------------------------------------------------
__global__ __launch_bounds__(1024) void k_softmax(const float* __restrict__ s,
                                                  float* __restrict__ w){
  __shared__ float red[1024];
  const int t = threadIdx.x;
  float m = -INFINITY;
  for (int i = t; i < LKEEP; i += 1024) m = fmaxf(m, s[i]);
  red[t] = m; __syncthreads();
  for (int st = 512; st > 0; st >>= 1){ if (t < st) red[t] = fmaxf(red[t], red[t + st]); __syncthreads(); }
  m = red[0]; __syncthreads();
  float z = 0.f;
  for (int i = t; i < LKEEP; i += 1024) z += expf(s[i] - m);
  red[t] = z; __syncthreads();
  for (int st = 512; st > 0; st >>= 1){ if (t < st) red[t] += red[t + st]; __syncthreads(); }
  const float invZ = 1.0f / red[0];
  for (int i = t; i < LKEEP; i += 1024) w[i] = expf(s[i] - m) * invZ;
}

// ---------------------------------------------------------------------------
// feat partials: grid (8 colblk x 64 rowblk).
// ---------------------------------------------------------------------------
__global__ __launch_bounds__(256) void k_feat1(const u16* __restrict__ hbf,
                                               const float* __restrict__ w,
                                               float* __restrict__ partial){
  const int t = threadIdx.x;
  const int colg = t & 7, rowpar = t >> 3;
  const int c0 = blockIdx.x * 64;
  const int j0 = blockIdx.y * 256;
  float acc[8] = {0.f};
  for (int j = j0 + rowpar; j < j0 + 256; j += 32){
    const float wj = w[j];
    short8 hv = *(const short8*)&hbf[(size_t)j * DMID + c0 + colg * 8];
    for (int c = 0; c < 8; c++) acc[c] += wj * bf2f((u16)hv[c]);
  }
  __shared__ float red[256 * 8];
  for (int c = 0; c < 8; c++) red[t * 8 + c] = acc[c];
  __syncthreads();
  for (int st = 128; st >= 8; st >>= 1){
    if (t < st){ for (int c = 0; c < 8; c++) red[t * 8 + c] += red[(t + st) * 8 + c]; }
    __syncthreads();
  }
  if (t < 8){
    for (int c = 0; c < 8; c++)
      partial[(size_t)blockIdx.y * DMID + c0 + t * 8 + c] = red[t * 8 + c];
  }
}

// ---------------------------------------------------------------------------
// Final: feat reduce (64 partials) + logits + soft-CE loss. One block x 512.
// ---------------------------------------------------------------------------
__global__ __launch_bounds__(512) void k_final(const float* __restrict__ partial,
                                               const float* __restrict__ teach,
                                               const float* __restrict__ Wp,
                                               const float* __restrict__ bp,
                                               float* __restrict__ out){
  __shared__ float red[512];
  const int t = threadIdx.x;
  float f = 0.f;
  for (int rb = 0; rb < 64; rb++) f += partial[(size_t)rb * DMID + t];
  const float td = teach[t];

  red[t] = f; __syncthreads();
  for (int st = 256; st > 0; st >>= 1){ if (t < st) red[t] = fmaxf(red[t], red[t + st]); __syncthreads(); }
  const float mf = red[0]; __syncthreads();

  red[t] = td; __syncthreads();
  for (int st = 256; st > 0; st >>= 1){ if (t < st) red[t] = fmaxf(red[t], red[t + st]); __syncthreads(); }
  const float mt = red[0]; __syncthreads();

  red[t] = expf(f - mf); __syncthreads();
  for (int st = 256; st > 0; st >>= 1){ if (t < st) red[t] += red[t + st]; __syncthreads(); }
  const float Zf = red[0]; __syncthreads();

  const float pt = expf(td - mt);
  red[t] = pt; __syncthreads();
  for (int st = 256; st > 0; st >>= 1){ if (t < st) red[t] += red[t + st]; __syncthreads(); }
  const float Zt = red[0]; __syncthreads();

  red[t] = pt * f; __syncthreads();
  for (int st = 256; st > 0; st >>= 1){ if (t < st) red[t] += red[t + st]; __syncthreads(); }
  const float S1 = red[0]; __syncthreads();

  red[t] = f * Wp[t * 2 + 0]; __syncthreads();
  for (int st = 256; st > 0; st >>= 1){ if (t < st) red[t] += red[t + st]; __syncthreads(); }
  const float L0 = red[0]; __syncthreads();

  red[t] = f * Wp[t * 2 + 1]; __syncthreads();
  for (int st = 256; st > 0; st >>= 1){ if (t < st) red[t] += red[t + st]; __syncthreads(); }
  const float L1 = red[0];

  if (t == 0){
    out[0] = L0 + bp[0];
    out[1] = L1 + bp[1];
    out[2] = (mf + logf(Zf)) - S1 / Zt;
  }
}

// ---------------------------------------------------------------------------
// ws layout (bytes):
//   [0)        keep_ids int[16384] | [65536) s f32[16384] | [131072) wgt f32[16384]
//   [200704)   wet bf16[512][1024] | [1249280) wa1t bf16[128][512]
//   [1380352)  scr: hist int[16384] (selection phase);
//              partial f32[64][512] @+0 (feat phase) — disjoint in time
//   [34934784) hbf bf16[16384][512]
// ---------------------------------------------------------------------------
extern "C" void kernel_launch(void* const* d_in, const int* in_sizes, int n_in,
                              void* d_out, int out_size, void* d_ws, size_t ws_size,
                              hipStream_t stream){
  const float* x     = (const float*)d_in[0];
  const float* attn  = (const float*)d_in[1];
  const float* teach = (const float*)d_in[2];
  const float* Wemb  = (const float*)d_in[3];
  const float* bemb  = (const float*)d_in[4];
  const float* Wa1   = (const float*)d_in[5];
  const float* ba1   = (const float*)d_in[6];
  const float* Wa2   = (const float*)d_in[7];
  const float* ba2   = (const float*)d_in[8];
  const float* Wp    = (const float*)d_in[9];
  const float* bp    = (const float*)d_in[10];
  float* out = (float*)d_out;

  char* ws = (char*)d_ws;
  int*   keep = (int*)(ws + 0);
  float* s    = (float*)(ws + 65536);
  float* wgt  = (float*)(ws + 131072);
  u16*   wet  = (u16*)(ws + 200704);
  u16*   wa1t = (u16*)(ws + 200704 + 1048576);
  char*  scr  = ws + 200704 + 1048576 + 131072;
  u16*   hbf  = (u16*)(ws + 200704 + 1048576 + 131072 + 33554432);

  int*   hist    = (int*)scr;
  float* partial = (float*)scr;   // reused after selection+gemm1

  k_prep<<<dim3(576), dim3(256), 0, stream>>>(Wemb, wet, Wa1, wa1t, hist);
  k_sel_hist<<<dim3(128), dim3(256), 0, stream>>>(attn, hist);
  k_sel_resolve<<<dim3(32), dim3(1024), 0, stream>>>(attn, hist, keep);
  k_gemm1g<<<dim3(512), dim3(256), 0, stream>>>(x, keep, wet, bemb, hbf);
  k_gemm2<<<dim3(LKEEP / 64), dim3(256), 0, stream>>>(hbf, wa1t, ba1, Wa2, ba2, s);
  k_softmax<<<dim3(1), dim3(1024), 0, stream>>>(s, wgt);
  k_feat1<<<dim3(8, 64), dim3(256), 0, stream>>>(hbf, wgt, partial);
  k_final<<<dim3(1), dim3(512), 0, stream>>>(partial, teach, Wp, bp, out);
}

// Round 17
// 146.210 us; speedup vs baseline: 1.4540x; 1.0468x over previous
//
#include <hip/hip_runtime.h>
#include <hip/hip_bf16.h>
#include <math.h>

// Problem constants
#define PS    32768
#define DIN   1024
#define DMID  512
#define DATT  128
#define KMASK 16384
#define LKEEP 16384

typedef unsigned short u16;
typedef __attribute__((ext_vector_type(8))) short short8;
typedef __attribute__((ext_vector_type(4))) float f32x4;

__device__ __forceinline__ u16 f2bf(float f){
  unsigned x = __float_as_uint(f);
  unsigned r = (x + 0x7fffu + ((x >> 16) & 1u)) >> 16;  // RNE
  return (u16)r;
}
__device__ __forceinline__ u16 f2bf_hw(float f){
  __hip_bfloat16 h = __float2bfloat16(f);    // RNE; pairs fuse to v_cvt_pk_bf16_f32
  return *reinterpret_cast<u16*>(&h);
}
__device__ __forceinline__ float bf2f(u16 u){
  return __uint_as_float(((unsigned)u) << 16);
}
// monotonic key: larger float -> larger unsigned
__device__ __forceinline__ unsigned fkey(float f){
  unsigned b = __float_as_uint(f);
  return (b & 0x80000000u) ? ~b : (b | 0x80000000u);
}

#define GLDS16(g,l) __builtin_amdgcn_global_load_lds( \
    (const __attribute__((address_space(1))) void*)(g), \
    (__attribute__((address_space(3))) void*)(l), 16, 0, 0)

// ---------------------------------------------------------------------------
// Prep: weight transposes (f32->bf16) + zero hist. 576 blocks.
// ---------------------------------------------------------------------------
__global__ __launch_bounds__(256) void k_prep(const float* __restrict__ Wemb,
                                              u16* __restrict__ wet,
                                              const float* __restrict__ Wa1,
                                              u16* __restrict__ wa1t,
                                              int* __restrict__ zbuf){
  __shared__ float tile[32][33];
  const int b = blockIdx.x, t = threadIdx.x;
  const int flat = b * 256 + t;
  if (flat < 16384) zbuf[flat] = 0;
  const int tx = t & 31, ty = t >> 5;
  if (b < 512){
    const int c0 = (b & 15) * 32, r0 = (b >> 4) * 32;   // Wemb [1024][512]
    for (int i = 0; i < 32; i += 8)
      tile[ty + i][tx] = Wemb[(size_t)(r0 + ty + i) * DMID + c0 + tx];
    __syncthreads();
    for (int i = 0; i < 32; i += 8)
      wet[(size_t)(c0 + ty + i) * DIN + r0 + tx] = f2bf(tile[tx][ty + i]);
  } else {
    const int b2 = b - 512;                              // Wa1 [512][128]
    const int c0 = (b2 & 3) * 32, r0 = (b2 >> 2) * 32;
    for (int i = 0; i < 32; i += 8)
      tile[ty + i][tx] = Wa1[(size_t)(r0 + ty + i) * DATT + c0 + tx];
    __syncthreads();
    for (int i = 0; i < 32; i += 8)
      wa1t[(size_t)(c0 + ty + i) * DMID + r0 + tx] = f2bf(tile[tx][ty + i]);
  }
}

// Stage 1: 14-bit global histogram. 128 blocks x 256.
__global__ __launch_bounds__(256) void k_sel_hist(const float* __restrict__ attn,
                                                  int* __restrict__ hist){
  const int i = blockIdx.x * 256 + threadIdx.x;
  const unsigned u = fkey(attn[i]);
  atomicAdd(&hist[u >> 18], 1);
}

// ---------------------------------------------------------------------------
// Stage 2 (fused scan+refine+cnt+write): 32 blocks x 1024 (R16-proven).
// ---------------------------------------------------------------------------
__global__ __launch_bounds__(1024) void k_sel_resolve(const float* __restrict__ attn,
                                                      const int* __restrict__ hist,
                                                      int* __restrict__ keep_ids){
  __shared__ int suf[1024];
  __shared__ unsigned ck[4096];
  __shared__ int ci[4096];
  __shared__ int sh_B, sh_kp, cnt;
  __shared__ unsigned sh_C;
  __shared__ int sh_thr;
  __shared__ int wbase[16];
  __shared__ int sh_base;
  const int t = threadIdx.x, b = blockIdx.x;

  // (a) suffix-scan of hist
  int local[16]; int s = 0;
  const int base = t * 16;
  for (int j = 0; j < 16; j++){ local[j] = hist[base + j]; s += local[j]; }
  suf[t] = s; __syncthreads();
  for (int off = 1; off < 1024; off <<= 1){
    int v = (t + off < 1024) ? suf[t + off] : 0;
    __syncthreads();
    suf[t] += v;
    __syncthreads();
  }
  const int above = (t < 1023) ? suf[t + 1] : 0;
  if (above < KMASK && KMASK <= suf[t]){
    int cum = above;
    for (int bb = 15; bb >= 0; bb--){
      int c = local[bb];
      if (cum + c >= KMASK){ sh_B = base + bb; sh_kp = KMASK - cum; break; }
      cum += c;
    }
  }
  if (t == 0) cnt = 0;
  __syncthreads();
  const unsigned B = (unsigned)sh_B;
  const int kp = sh_kp;

  // (b) collect candidates + rank-select (order-independent result)
  for (int i = t; i < PS; i += 1024){
    unsigned u = fkey(attn[i]);
    if ((u >> 18) == B){
      int p = atomicAdd(&cnt, 1);
      if (p < 4096){ ck[p] = u; ci[p] = i; }
    }
  }
  __syncthreads();
  int n = cnt; if (n > 4096) n = 4096;
  for (int p = t; p < n; p += 1024){
    const unsigned mk = ck[p]; const int mi = ci[p];
    int rank = 0;
    for (int j = 0; j < n; j++){
      const unsigned kj = ck[j];
      rank += (kj > mk) || (kj == mk && ci[j] < mi);
    }
    if (rank == kp - 1){ sh_C = mk; sh_thr = mi; }
  }
  __syncthreads();
  const unsigned C = sh_C;
  const int thr = sh_thr;

  // (c) stable compaction of this block's chunk
  const int i = b * 1024 + t;
  const unsigned u = fkey(attn[i]);
  const bool kept = (u < C) || (u == C && i > thr);
  const unsigned long long bal = __ballot(kept);
  const int lane = t & 63, w = t >> 6;
  if (lane == 0) wbase[w] = __popcll(bal);
  int cnt2 = 0;
  for (int j = t; j < b * 1024; j += 1024){
    const unsigned u2 = fkey(attn[j]);
    cnt2 += (u2 < C) || (u2 == C && j > thr);
  }
  suf[t] = cnt2; __syncthreads();
  for (int st = 512; st > 0; st >>= 1){ if (t < st) suf[t] += suf[t + st]; __syncthreads(); }
  if (t == 0){
    sh_base = suf[0];
    int run = 0;
    for (int j = 0; j < 16; j++){ int c = wbase[j]; wbase[j] = run; run += c; }
  }
  __syncthreads();
  if (kept){
    const int lr = __popcll(bal & ((1ull << lane) - 1ull));
    keep_ids[sh_base + wbase[w] + lr] = i;
  }
}

// ---------------------------------------------------------------------------
// GEMM1 fused gather (exact R6-proven body).
// ---------------------------------------------------------------------------
__global__ __launch_bounds__(256) void k_gemm1g(const float* __restrict__ xg,
                                                const int* __restrict__ keep,
                                                const u16* __restrict__ wet,
                                                const float* __restrict__ bemb,
                                                u16* __restrict__ hbf){
  __shared__ __align__(16) u16 As[128 * 32];
  __shared__ __align__(16) u16 Bs[128 * 32];
  const int t = threadIdx.x;
  const int wid = t >> 6, lane = t & 63;
  const int g = lane >> 4, li = lane & 15;
  const int m_ = blockIdx.x;
  const int by = (m_ & 7) + 8 * (m_ >> 5);
  const int bx = (m_ >> 3) & 3;
  const int brow = by * 128, bcol = bx * 128;
  const int wrow0 = (wid >> 1) * 64, wcol0 = (wid & 1) * 64;

  f32x4 acc[4][4];
  for (int mm = 0; mm < 4; mm++)
    for (int nn = 0; nn < 4; nn++)
      acc[mm][nn] = (f32x4){0.f, 0.f, 0.f, 0.f};

  const int rsub = t >> 3, csub = t & 7;
  const float* gA[4];
#pragma unroll
  for (int q = 0; q < 4; q++){
    const int rid = keep[brow + q * 32 + rsub];
    gA[q] = xg + (size_t)rid * DIN + csub * 4;
  }
  const int r4 = lane >> 2, cB = lane & 3;
  const u16* gB = wet + ((size_t)(bcol + wid * 32 + r4) * DIN + cB * 8);
  u16* lB = Bs + wid * 1024;

  for (int k0 = 0; k0 < DIN; k0 += 32){
    float4 av[4];
#pragma unroll
    for (int q = 0; q < 4; q++) av[q] = *(const float4*)(gA[q] + k0);
    GLDS16(gB + k0,            lB);
    GLDS16(gB + 16 * DIN + k0, lB + 512);
#pragma unroll
    for (int q = 0; q < 4; q++){
      ushort4 pk;
      pk.x = f2bf_hw(av[q].x); pk.y = f2bf_hw(av[q].y);
      pk.z = f2bf_hw(av[q].z); pk.w = f2bf_hw(av[q].w);
      *(ushort4*)&As[(q * 32 + rsub) * 32 + csub * 4] = pk;
    }
    __syncthreads();
    short8 a[4], b[4];
#pragma unroll
    for (int mm = 0; mm < 4; mm++)
      a[mm] = *(const short8*)&As[(wrow0 + mm * 16 + li) * 32 + g * 8];
#pragma unroll
    for (int nn = 0; nn < 4; nn++)
      b[nn] = *(const short8*)&Bs[(wcol0 + nn * 16 + li) * 32 + g * 8];
    for (int mm = 0; mm < 4; mm++)
      for (int nn = 0; nn < 4; nn++)
        acc[mm][nn] = __builtin_amdgcn_mfma_f32_16x16x32_bf16(a[mm], b[nn], acc[mm][nn], 0, 0, 0);
    __syncthreads();
  }

  for (int nn = 0; nn < 4; nn++){
    const int col = bcol + wcol0 + nn * 16 + li;
    const float be = bemb[col];
    for (int mm = 0; mm < 4; mm++){
      const int row0 = brow + wrow0 + mm * 16 + g * 4;
      f32x4 v = acc[mm][nn];
      for (int r = 0; r < 4; r++){
        float val = v[r] + be;
        if (val < 0.f) val = 0.f;
        hbf[(size_t)(row0 + r) * DMID + col] = f2bf(val);
      }
    }
  }
}

// ---------------------------------------------------------------------------
// GEMM2 + gelu + W_a2 dot -> s; epilogue: per-block (max,sumexp) over its
// 64 rows -> smax[b], ssum[b] (R11-verified logic).
// ---------------------------------------------------------------------------
__global__ __launch_bounds__(256) void k_gemm2(const u16* __restrict__ hbf,
                                               const u16* __restrict__ wa1t,
                                               const float* __restrict__ ba1,
                                               const float* __restrict__ wa2,
                                               const float* __restrict__ ba2,
                                               float* __restrict__ s_out,
                                               float* __restrict__ smax,
                                               float* __restrict__ ssum){
  __shared__ __align__(16) u16 As[64 * 32];
  __shared__ __align__(16) u16 Bs[128 * 32];
  const int t = threadIdx.x;
  const int wid = t >> 6, lane = t & 63;
  const int g = lane >> 4, li = lane & 15;
  const int brow = blockIdx.x * 64;
  const int wrow0 = (wid >> 1) * 32, wcol0 = (wid & 1) * 64;

  f32x4 acc[2][4];
  for (int m = 0; m < 2; m++)
    for (int n = 0; n < 4; n++)
      acc[m][n] = (f32x4){0.f, 0.f, 0.f, 0.f};

  const int r4 = lane >> 2, c4 = lane & 3;
  const u16* gA = hbf  + ((size_t)(brow + wid * 16 + r4) * DMID + c4 * 8);
  const u16* gB = wa1t + ((size_t)(wid * 32 + r4) * DMID + c4 * 8);
  u16* lA = As + wid * 512;
  u16* lB = Bs + wid * 1024;

  for (int k0 = 0; k0 < DMID; k0 += 32){
    GLDS16(gA + k0,             lA);
    GLDS16(gB + k0,             lB);
    GLDS16(gB + 16 * DMID + k0, lB + 512);
    __syncthreads();
    short8 a[2], b[4];
    for (int m = 0; m < 2; m++)
      a[m] = *(const short8*)&As[(wrow0 + m * 16 + li) * 32 + g * 8];
    for (int n = 0; n < 4; n++)
      b[n] = *(const short8*)&Bs[(wcol0 + n * 16 + li) * 32 + g * 8];
    for (int m = 0; m < 2; m++)
      for (int n = 0; n < 4; n++)
        acc[m][n] = __builtin_amdgcn_mfma_f32_16x16x32_bf16(a[m], b[n], acc[m][n], 0, 0, 0);
    __syncthreads();
  }

  float rsum[2][4] = {{0.f,0.f,0.f,0.f},{0.f,0.f,0.f,0.f}};
  for (int n = 0; n < 4; n++){
    const int col = wcol0 + n * 16 + li;
    const float b1 = ba1[col], w2 = wa2[col];
    for (int m = 0; m < 2; m++){
      f32x4 v = acc[m][n];
      for (int r = 0; r < 4; r++){
        float xv = v[r] + b1;
        float ge = 0.5f * xv * (1.0f + erff(xv * 0.70710678118654752f)); // exact gelu
        rsum[m][r] += ge * w2;
      }
    }
  }
  const float bb = ba2[0];
  for (int m = 0; m < 2; m++){
    for (int r = 0; r < 4; r++){
      float v = rsum[m][r];
      v += __shfl_xor(v, 1); v += __shfl_xor(v, 2);
      v += __shfl_xor(v, 4); v += __shfl_xor(v, 8);
      if (li == 0) s_out[brow + wrow0 + m * 16 + g * 4 + r] = v + bb;
    }
  }
  __syncthreads();   // s writes visible block-wide
  if (t < 64){
    const float sv = s_out[brow + t];
    float mx = sv;
    for (int off = 1; off < 64; off <<= 1) mx = fmaxf(mx, __shfl_xor(mx, off));
    float ez = expf(sv - mx);
    for (int off = 1; off < 64; off <<= 1) ez += __shfl_xor(ez, off);
    if (t == 0){ smax[blockIdx.x] = mx; ssum[blockIdx.x] = ez; }
  }
}

// ---------------------------------------------------------------------------
// feat1: combine 256 softmax stat pairs -> (m, invZ) (deterministic, identical
// in every block; ~1us); then weighted partial sums. Grid (8 x 64).
// ---------------------------------------------------------------------------
__global__ __launch_bounds__(256) void k_feat1(const u16* __restrict__ hbf,
                                               const float* __restrict__ s,
                                               const float* __restrict__ smax,
                                               const float* __restrict__ ssum,
                                               float* __restrict__ partial){
  __shared__ float red[256 * 8];
  const int t = threadIdx.x;

  red[t] = smax[t]; __syncthreads();
  for (int st = 128; st >= 1; st >>= 1){ if (t < st) red[t] = fmaxf(red[t], red[t + st]); __syncthreads(); }
  const float m = red[0]; __syncthreads();
  red[t] = ssum[t] * expf(smax[t] - m); __syncthreads();
  for (int st = 128; st >= 1; st >>= 1){ if (t < st) red[t] += red[t + st]; __syncthreads(); }
  const float invZ = 1.0f / red[0]; __syncthreads();

  const int colg = t & 7, rowpar = t >> 3;
  const int c0 = blockIdx.x * 64;
  const int j0 = blockIdx.y * 256;
  float acc[8] = {0.f,0.f,0.f,0.f,0.f,0.f,0.f,0.f};
  for (int j = j0 + rowpar; j < j0 + 256; j += 32){
    const float wj = expf(s[j] - m) * invZ;
    short8 hv = *(const short8*)&hbf[(size_t)j * DMID + c0 + colg * 8];
    for (int c = 0; c < 8; c++) acc[c] += wj * bf2f((u16)hv[c]);
  }
  for (int c = 0; c < 8; c++) red[t * 8 + c] = acc[c];
  __syncthreads();
  for (int st = 128; st >= 8; st >>= 1){
    if (t < st){ for (int c = 0; c < 8; c++) red[t * 8 + c] += red[(t + st) * 8 + c]; }
    __syncthreads();
  }
  if (t < 8){
    for (int c = 0; c < 8; c++)
      partial[(size_t)blockIdx.y * DMID + c0 + t * 8 + c] = red[t * 8 + c];
  }
}

// ---------------------------------------------------------------------------
// Final: feat reduce (64 partials) + logits + soft-CE loss. One block x 512.
// ---------------------------------------------------------------------------
__global__ __launch_bounds__(512) void k_final(const float* __restrict__ partial,
                                               const float* __restrict__ teach,
                                               const float* __restrict__ Wp,
                                               const float* __restrict__ bp,
                                               float* __restrict__ out){
  __shared__ float red[512];
  const int t = threadIdx.x;
  float f = 0.f;
  for (int rb = 0; rb < 64; rb++) f += partial[(size_t)rb * DMID + t];
  const float td = teach[t];

  red[t] = f; __syncthreads();
  for (int st = 256; st > 0; st >>= 1){ if (t < st) red[t] = fmaxf(red[t], red[t + st]); __syncthreads(); }
  const float mf = red[0]; __syncthreads();

  red[t] = td; __syncthreads();
  for (int st = 256; st > 0; st >>= 1){ if (t < st) red[t] = fmaxf(red[t], red[t + st]); __syncthreads(); }
  const float mt = red[0]; __syncthreads();

  red[t] = expf(f - mf); __syncthreads();
  for (int st = 256; st > 0; st >>= 1){ if (t < st) red[t] += red[t + st]; __syncthreads(); }
  const float Zf = red[0]; __syncthreads();

  const float pt = expf(td - mt);
  red[t] = pt; __syncthreads();
  for (int st = 256; st > 0; st >>= 1){ if (t < st) red[t] += red[t + st]; __syncthreads(); }
  const float Zt = red[0]; __syncthreads();

  red[t] = pt * f; __syncthreads();
  for (int st = 256; st > 0; st >>= 1){ if (t < st) red[t] += red[t + st]; __syncthreads(); }
  const float S1 = red[0]; __syncthreads();

  red[t] = f * Wp[t * 2 + 0]; __syncthreads();
  for (int st = 256; st > 0; st >>= 1){ if (t < st) red[t] += red[t + st]; __syncthreads(); }
  const float L0 = red[0]; __syncthreads();

  red[t] = f * Wp[t * 2 + 1]; __syncthreads();
  for (int st = 256; st > 0; st >>= 1){ if (t < st) red[t] += red[t + st]; __syncthreads(); }
  const float L1 = red[0];

  if (t == 0){
    out[0] = L0 + bp[0];
    out[1] = L1 + bp[1];
    out[2] = (mf + logf(Zf)) - S1 / Zt;
  }
}

// ---------------------------------------------------------------------------
// ws layout (bytes):
//   [0)        keep_ids int[16384] | [65536) s f32[16384]
//   [131072)   smax f32[256] | [132096) ssum f32[256]
//   [200704)   wet bf16[512][1024] | [1249280) wa1t bf16[128][512]
//   [1380352)  scr: hist int[16384] (selection phase);
//              partial f32[64][512] @+0 (feat phase) — disjoint in time
//   [34934784) hbf bf16[16384][512]
// ---------------------------------------------------------------------------
extern "C" void kernel_launch(void* const* d_in, const int* in_sizes, int n_in,
                              void* d_out, int out_size, void* d_ws, size_t ws_size,
                              hipStream_t stream){
  const float* x     = (const float*)d_in[0];
  const float* attn  = (const float*)d_in[1];
  const float* teach = (const float*)d_in[2];
  const float* Wemb  = (const float*)d_in[3];
  const float* bemb  = (const float*)d_in[4];
  const float* Wa1   = (const float*)d_in[5];
  const float* ba1   = (const float*)d_in[6];
  const float* Wa2   = (const float*)d_in[7];
  const float* ba2   = (const float*)d_in[8];
  const float* Wp    = (const float*)d_in[9];
  const float* bp    = (const float*)d_in[10];
  float* out = (float*)d_out;

  char* ws = (char*)d_ws;
  int*   keep = (int*)(ws + 0);
  float* s    = (float*)(ws + 65536);
  float* smax = (float*)(ws + 131072);
  float* ssum = (float*)(ws + 132096);
  u16*   wet  = (u16*)(ws + 200704);
  u16*   wa1t = (u16*)(ws + 200704 + 1048576);
  char*  scr  = ws + 200704 + 1048576 + 131072;
  u16*   hbf  = (u16*)(ws + 200704 + 1048576 + 131072 + 33554432);

  int*   hist    = (int*)scr;
  float* partial = (float*)scr;   // reused after selection+gemm1

  k_prep<<<dim3(576), dim3(256), 0, stream>>>(Wemb, wet, Wa1, wa1t, hist);
  k_sel_hist<<<dim3(128), dim3(256), 0, stream>>>(attn, hist);
  k_sel_resolve<<<dim3(32), dim3(1024), 0, stream>>>(attn, hist, keep);
  k_gemm1g<<<dim3(512), dim3(256), 0, stream>>>(x, keep, wet, bemb, hbf);
  k_gemm2<<<dim3(LKEEP / 64), dim3(256), 0, stream>>>(hbf, wa1t, ba1, Wa2, ba2, s, smax, ssum);
  k_feat1<<<dim3(8, 64), dim3(256), 0, stream>>>(hbf, s, smax, ssum, partial);
  k_final<<<dim3(1), dim3(512), 0, stream>>>(partial, teach, Wp, bp, out);
}